// Round 1
// baseline (608.676 us; speedup 1.0000x reference)
//
#include <hip/hip_runtime.h>

#define NN 50000
#define CH 256            // output channels of both layers

static __device__ __forceinline__ float4 ld4(const float* p){ return *(const float4*)p; }

// ---------------- CSR build ----------------

__global__ void hist_kernel(const int* __restrict__ dst, int* __restrict__ cnt, int E){
  int e = blockIdx.x*256 + threadIdx.x;
  if (e < E) atomicAdd(&cnt[dst[e]], 1);
}

__global__ void dinv_kernel(const int* __restrict__ cnt, float* __restrict__ dinv, int n){
  int i = blockIdx.x*256 + threadIdx.x;
  if (i < n) dinv[i] = rsqrtf(1.0f + (float)cnt[i]);
}

__global__ void scan_partial_kernel(const int* __restrict__ cnt, int* __restrict__ bsum, int n){
  __shared__ int sd[256];
  int t = threadIdx.x;
  int base = blockIdx.x*1024 + t*4;
  int s = 0;
  #pragma unroll
  for (int j=0;j<4;j++){ int idx = base+j; if (idx<n) s += cnt[idx]; }
  sd[t] = s; __syncthreads();
  for (int off=128; off>0; off>>=1){ if (t<off) sd[t]+=sd[t+off]; __syncthreads(); }
  if (t==0) bsum[blockIdx.x] = sd[0];
}

__global__ void scan_bsums_kernel(int* __restrict__ bsum, int nb){
  if (threadIdx.x==0 && blockIdx.x==0){
    int run=0;
    for (int i=0;i<nb;i++){ int v=bsum[i]; bsum[i]=run; run+=v; }
  }
}

__global__ void scan_final_kernel(const int* __restrict__ cnt, const int* __restrict__ bsum,
                                  int* __restrict__ offs, int* __restrict__ cursor, int n, int total){
  __shared__ int sd[256];
  int t = threadIdx.x;
  int base = blockIdx.x*1024 + t*4;
  int v[4]; int s=0;
  #pragma unroll
  for (int j=0;j<4;j++){ int idx=base+j; v[j] = (idx<n)?cnt[idx]:0; s += v[j]; }
  sd[t]=s; __syncthreads();
  for (int off=1; off<256; off<<=1){
    int x = (t>=off)? sd[t-off] : 0;
    __syncthreads();
    sd[t] += x;
    __syncthreads();
  }
  int run = bsum[blockIdx.x] + sd[t] - s;   // exclusive prefix for this thread's chunk
  #pragma unroll
  for (int j=0;j<4;j++){
    int idx=base+j;
    if (idx<n){ offs[idx]=run; cursor[idx]=run; }
    run += v[j];
  }
  if (blockIdx.x==0 && t==0) offs[n] = total;
}

__global__ void scatter_kernel(const int* __restrict__ src, const int* __restrict__ dst,
                               const float* __restrict__ dinv, int* __restrict__ cursor,
                               int* __restrict__ esrc, float* __restrict__ enorm, int E){
  int e = blockIdx.x*256 + threadIdx.x;
  if (e < E){
    int d = dst[e], s = src[e];
    int pos = atomicAdd(&cursor[d], 1);
    esrc[pos] = s;
    enorm[pos] = dinv[s]*dinv[d];
  }
}

// ---------------- fp32 GEMM: C[m][n] = sum_k A[m*K+k] * W[n*K+k]  (N fixed = 256) ----------------
// BM=64, BN=64, BK=16, 256 threads, 4x4 microtile.

__global__ __launch_bounds__(256) void gemm_bt_kernel(const float* __restrict__ A,
                                                      const float* __restrict__ W,
                                                      float* __restrict__ C, int M, int K){
  __shared__ float As[16][64];
  __shared__ float Bs[16][64];
  int bm = blockIdx.x, bn = blockIdx.y;
  int tid = threadIdx.x;
  int lm = tid >> 2;          // 0..63 : row within tile for staging
  int lk = (tid & 3) * 4;     // 0,4,8,12 : k offset for staging (float4)
  int tx = tid & 15;          // m-microtile index
  int ty = tid >> 4;          // n-microtile index
  float acc[4][4] = {};

  int rowA = bm*64 + lm;
  bool aval = rowA < M;
  const float* Aptr = A + (size_t)rowA*K + lk;
  const float* Wptr = W + (size_t)(bn*64 + lm)*K + lk;

  for (int k0 = 0; k0 < K; k0 += 16){
    float4 av = aval ? ld4(Aptr + k0) : make_float4(0.f,0.f,0.f,0.f);
    float4 wv = ld4(Wptr + k0);
    As[lk+0][lm]=av.x; As[lk+1][lm]=av.y; As[lk+2][lm]=av.z; As[lk+3][lm]=av.w;
    Bs[lk+0][lm]=wv.x; Bs[lk+1][lm]=wv.y; Bs[lk+2][lm]=wv.z; Bs[lk+3][lm]=wv.w;
    __syncthreads();
    #pragma unroll
    for (int k=0;k<16;k++){
      float4 a4 = *(const float4*)&As[k][tx*4];
      float4 b4 = *(const float4*)&Bs[k][ty*4];
      float a[4] = {a4.x,a4.y,a4.z,a4.w};
      float b[4] = {b4.x,b4.y,b4.z,b4.w};
      #pragma unroll
      for (int i=0;i<4;i++)
        #pragma unroll
        for (int j=0;j<4;j++)
          acc[i][j] += a[i]*b[j];
    }
    __syncthreads();
  }

  #pragma unroll
  for (int i=0;i<4;i++){
    int row = bm*64 + tx*4 + i;
    if (row < M){
      float4 o = make_float4(acc[i][0],acc[i][1],acc[i][2],acc[i][3]);
      *(float4*)&C[(size_t)row*CH + bn*64 + ty*4] = o;
    }
  }
}

// ---------------- aggregation: out[i] = (relu?) sum_e h[src]*norm + h[i]*dinv_i^2 + b ----------------
// one wave per node, lane covers 4 channels (256 ch / 64 lanes).

template<bool RELU>
__global__ __launch_bounds__(256) void aggregate_kernel(const float* __restrict__ h,
                                                        const float* __restrict__ bias,
                                                        const float* __restrict__ dinv,
                                                        const int* __restrict__ offs,
                                                        const int* __restrict__ esrc,
                                                        const float* __restrict__ enorm,
                                                        float* __restrict__ out, int n){
  int wave = threadIdx.x >> 6;
  int lane = threadIdx.x & 63;
  int i = blockIdx.x*4 + wave;
  if (i >= n) return;
  int c = lane*4;
  float di = dinv[i];
  float w = di*di;
  float4 b4 = ld4(bias + c);
  float4 hv = ld4(h + (size_t)i*CH + c);
  float4 acc = make_float4(hv.x*w + b4.x, hv.y*w + b4.y, hv.z*w + b4.z, hv.w*w + b4.w);
  int e0 = offs[i], e1 = offs[i+1];
  for (int e = e0; e < e1; ++e){
    int s = esrc[e];
    float nm = enorm[e];
    float4 hs = ld4(h + (size_t)s*CH + c);
    acc.x += hs.x*nm; acc.y += hs.y*nm; acc.z += hs.z*nm; acc.w += hs.w*nm;
  }
  if (RELU){
    acc.x = fmaxf(acc.x,0.f); acc.y = fmaxf(acc.y,0.f);
    acc.z = fmaxf(acc.z,0.f); acc.w = fmaxf(acc.w,0.f);
  }
  *(float4*)(out + (size_t)i*CH + c) = acc;
}

// ---------------- launch ----------------

extern "C" void kernel_launch(void* const* d_in, const int* in_sizes, int n_in,
                              void* d_out, int out_size, void* d_ws, size_t ws_size,
                              hipStream_t stream){
  const float* x  = (const float*)d_in[0];
  const int*   ei = (const int*)d_in[1];
  const float* W1 = (const float*)d_in[2];
  const float* b1 = (const float*)d_in[3];
  const float* W2 = (const float*)d_in[4];
  const float* b2 = (const float*)d_in[5];
  float* out = (float*)d_out;

  const int n = NN;
  const int E = in_sizes[1] / 2;
  const int* src = ei;
  const int* dst = ei + E;
  const int KIN = in_sizes[0] / n;   // 512

  char* ws = (char*)d_ws;
  size_t off = 0;
  auto alloc = [&](size_t bytes)->char* {
    char* p = ws + off;
    off += (bytes + 255) & ~(size_t)255;
    return p;
  };
  float* hbuf   = (float*)alloc((size_t)n*CH*sizeof(float));  // 51.2 MB intermediate
  float* dinv   = (float*)alloc((size_t)n*sizeof(float));
  int*   cnt    = (int*)  alloc((size_t)n*sizeof(int));
  int*   offs   = (int*)  alloc((size_t)(n+1)*sizeof(int));
  int*   cursor = (int*)  alloc((size_t)n*sizeof(int));
  int*   bsum   = (int*)  alloc(256*sizeof(int));
  int*   esrc   = (int*)  alloc((size_t)E*sizeof(int));
  float* enorm  = (float*)alloc((size_t)E*sizeof(float));
  (void)ws_size;

  // --- CSR + norms (rebuilt every call; ws is re-poisoned) ---
  hipMemsetAsync(cnt, 0, (size_t)n*sizeof(int), stream);
  hist_kernel<<<(E+255)/256, 256, 0, stream>>>(dst, cnt, E);
  dinv_kernel<<<(n+255)/256, 256, 0, stream>>>(cnt, dinv, n);
  int nb = (n + 1023) / 1024;
  scan_partial_kernel<<<nb, 256, 0, stream>>>(cnt, bsum, n);
  scan_bsums_kernel<<<1, 64, 0, stream>>>(bsum, nb);
  scan_final_kernel<<<nb, 256, 0, stream>>>(cnt, bsum, offs, cursor, n, E);
  scatter_kernel<<<(E+255)/256, 256, 0, stream>>>(src, dst, dinv, cursor, esrc, enorm, E);

  // --- layer 1: hbuf = x @ W1^T ; out(h1) = relu(agg(hbuf) + b1) ---
  dim3 gg((n+63)/64, CH/64);
  gemm_bt_kernel<<<gg, 256, 0, stream>>>(x, W1, hbuf, n, KIN);
  aggregate_kernel<true><<<(n+3)/4, 256, 0, stream>>>(hbuf, b1, dinv, offs, esrc, enorm, out, n);

  // --- layer 2: hbuf = h1 @ W2^T ; out = agg(hbuf) + b2 ---
  gemm_bt_kernel<<<gg, 256, 0, stream>>>(out, W2, hbuf, n, CH);
  aggregate_kernel<false><<<(n+3)/4, 256, 0, stream>>>(hbuf, b2, dinv, offs, esrc, enorm, out, n);
}

// Round 2
// 356.939 us; speedup vs baseline: 1.7053x; 1.7053x over previous
//
#include <hip/hip_runtime.h>

#define NN 50000
#define CH 256            // output channels of both layers

typedef unsigned short u16;
typedef unsigned int   u32;

using short8 = __attribute__((ext_vector_type(8))) short;
using f32x4  = __attribute__((ext_vector_type(4))) float;

static __device__ __forceinline__ float4 ld4(const float* p){ return *(const float4*)p; }

// fp32 -> bf16 round-to-nearest-even
static __device__ __forceinline__ u16 f2b(float f){
  u32 u = __float_as_uint(f);
  u = (u + 0x7fffu + ((u >> 16) & 1u)) >> 16;
  return (u16)u;
}
static __device__ __forceinline__ float b2f(u16 b){
  return __uint_as_float(((u32)b) << 16);
}

// ---------------- CSR build ----------------

__global__ void hist_kernel(const int* __restrict__ dst, int* __restrict__ cnt, int E){
  int e = blockIdx.x*256 + threadIdx.x;
  if (e < E) atomicAdd(&cnt[dst[e]], 1);
}

__global__ void dinv_kernel(const int* __restrict__ cnt, float* __restrict__ dinv, int n){
  int i = blockIdx.x*256 + threadIdx.x;
  if (i < n) dinv[i] = rsqrtf(1.0f + (float)cnt[i]);
}

__global__ void scan_partial_kernel(const int* __restrict__ cnt, int* __restrict__ bsum, int n){
  __shared__ int sd[256];
  int t = threadIdx.x;
  int base = blockIdx.x*1024 + t*4;
  int s = 0;
  #pragma unroll
  for (int j=0;j<4;j++){ int idx = base+j; if (idx<n) s += cnt[idx]; }
  sd[t] = s; __syncthreads();
  for (int off=128; off>0; off>>=1){ if (t<off) sd[t]+=sd[t+off]; __syncthreads(); }
  if (t==0) bsum[blockIdx.x] = sd[0];
}

// single-wave exclusive scan of block sums (nb <= 64)
__global__ void scan_bsums_kernel(int* __restrict__ bsum, int nb){
  int t = threadIdx.x;
  int v = (t < nb) ? bsum[t] : 0;
  int orig = v;
  #pragma unroll
  for (int off=1; off<64; off<<=1){
    int u = __shfl_up(v, off, 64);
    if (t >= off) v += u;
  }
  if (t < nb) bsum[t] = v - orig;  // exclusive
}

__global__ void scan_final_kernel(const int* __restrict__ cnt, const int* __restrict__ bsum,
                                  int* __restrict__ offs, int* __restrict__ cursor, int n, int total){
  __shared__ int sd[256];
  int t = threadIdx.x;
  int base = blockIdx.x*1024 + t*4;
  int v[4]; int s=0;
  #pragma unroll
  for (int j=0;j<4;j++){ int idx=base+j; v[j] = (idx<n)?cnt[idx]:0; s += v[j]; }
  sd[t]=s; __syncthreads();
  for (int off=1; off<256; off<<=1){
    int x = (t>=off)? sd[t-off] : 0;
    __syncthreads();
    sd[t] += x;
    __syncthreads();
  }
  int run = bsum[blockIdx.x] + sd[t] - s;   // exclusive prefix for this thread's chunk
  #pragma unroll
  for (int j=0;j<4;j++){
    int idx=base+j;
    if (idx<n){ offs[idx]=run; cursor[idx]=run; }
    run += v[j];
  }
  if (blockIdx.x==0 && t==0) offs[n] = total;
}

__global__ void scatter_kernel(const int* __restrict__ src, const int* __restrict__ dst,
                               const float* __restrict__ dinv, int* __restrict__ cursor,
                               int* __restrict__ esrc, float* __restrict__ enorm, int E){
  int e = blockIdx.x*256 + threadIdx.x;
  if (e < E){
    int d = dst[e], s = src[e];
    int pos = atomicAdd(&cursor[d], 1);
    esrc[pos] = s;
    enorm[pos] = dinv[s]*dinv[d];
  }
}

// ---------------- fp32 -> bf16 conversion ----------------

__global__ __launch_bounds__(256) void cvt_kernel(const float* __restrict__ in,
                                                  u16* __restrict__ out, int n4){
  int i = blockIdx.x*256 + threadIdx.x;
  if (i >= n4) return;
  float4 v = ld4(in + (size_t)i*4);
  ushort4 o;
  o.x = f2b(v.x); o.y = f2b(v.y); o.z = f2b(v.z); o.w = f2b(v.w);
  *(ushort4*)(out + (size_t)i*4) = o;
}

// ---------------- bf16 MFMA GEMM (m97 structure) ----------------
// C[m][n] = sum_k A[m*K+k]*B[n*K+k], output bf16, N fixed = 256, BN=128.
// BM=128, BK=32, 256 threads (4 waves), wave computes 64x64 via 4x4 of 16x16x32.

static __device__ __forceinline__ void gload_lds16(const u16* g, u16* l){
  __builtin_amdgcn_global_load_lds((const __attribute__((address_space(1))) void*)g,
                                   (__attribute__((address_space(3))) void*)l, 16, 0, 0);
}

__global__ __launch_bounds__(256) void gemm_mfma_kernel(const u16* __restrict__ A,
                                                        const u16* __restrict__ B,
                                                        u16* __restrict__ C,
                                                        int M, int K){
  __shared__ u16 As[128*32];
  __shared__ u16 Bs[128*32];
  int tid = threadIdx.x;
  int wave = tid >> 6, lane = tid & 63;
  int bm = blockIdx.x, bn = blockIdx.y;

  // staging: element e = (issue*256 + tid)*8 ; row = issue*64 + tid/4 ; col = (tid&3)*8
  int sr = tid >> 2;
  int sc = (tid & 3) * 8;
  int ar0 = bm*128 + sr;       if (ar0 > M-1) ar0 = M-1;
  int ar1 = bm*128 + 64 + sr;  if (ar1 > M-1) ar1 = M-1;
  const u16* ga0 = A + (size_t)ar0*K + sc;
  const u16* ga1 = A + (size_t)ar1*K + sc;
  const u16* gb0 = B + (size_t)(bn*128 + sr)*K + sc;
  const u16* gb1 = B + (size_t)(bn*128 + 64 + sr)*K + sc;
  // wave-uniform LDS bases; HW adds lane*16B
  u16* la0 = As + (size_t)(wave*64)*8;
  u16* la1 = As + (size_t)(256 + wave*64)*8;
  u16* lb0 = Bs + (size_t)(wave*64)*8;
  u16* lb1 = Bs + (size_t)(256 + wave*64)*8;

  int wm = wave & 1, wn = wave >> 1;
  int lm = lane & 15;
  int lk = (lane >> 4) * 8;

  f32x4 acc[4][4] = {};

  for (int k0 = 0; k0 < K; k0 += 32){
    gload_lds16(ga0 + k0, la0);
    gload_lds16(ga1 + k0, la1);
    gload_lds16(gb0 + k0, lb0);
    gload_lds16(gb1 + k0, lb1);
    __syncthreads();   // compiler drains vmcnt before barrier
    short8 af[4], bfr[4];
    #pragma unroll
    for (int i=0;i<4;i++)
      af[i] = *(const short8*)&As[(size_t)(wm*64 + i*16 + lm)*32 + lk];
    #pragma unroll
    for (int j=0;j<4;j++)
      bfr[j] = *(const short8*)&Bs[(size_t)(wn*64 + j*16 + lm)*32 + lk];
    #pragma unroll
    for (int i=0;i<4;i++)
      #pragma unroll
      for (int j=0;j<4;j++)
        acc[i][j] = __builtin_amdgcn_mfma_f32_16x16x32_bf16(af[i], bfr[j], acc[i][j], 0, 0, 0);
    __syncthreads();
  }

  // C/D layout: row=(lane>>4)*4+reg, col=lane&15 (m89-verified)
  int rb = (lane >> 4) * 4;
  #pragma unroll
  for (int i=0;i<4;i++){
    #pragma unroll
    for (int r=0;r<4;r++){
      int row = bm*128 + wm*64 + i*16 + rb + r;
      if (row < M){
        #pragma unroll
        for (int j=0;j<4;j++){
          int col = bn*128 + wn*64 + j*16 + lm;
          C[(size_t)row*CH + col] = f2b(acc[i][j][r]);
        }
      }
    }
  }
}

// ---------------- aggregation (bf16 in): out[i] = (relu?) sum_e h[src]*norm + h[i]*dinv_i^2 + b ----
// one wave per node; lane covers 4 channels (ushort4 = 8B loads).

template<bool RELU, bool OUTBF>
__global__ __launch_bounds__(256) void aggregate_kernel(const u16* __restrict__ h,
                                                        const float* __restrict__ bias,
                                                        const float* __restrict__ dinv,
                                                        const int* __restrict__ offs,
                                                        const int* __restrict__ esrc,
                                                        const float* __restrict__ enorm,
                                                        void* __restrict__ outv, int n){
  int wave = threadIdx.x >> 6;
  int lane = threadIdx.x & 63;
  int i = blockIdx.x*4 + wave;
  if (i >= n) return;
  int c = lane*4;
  float di = dinv[i];
  float w = di*di;
  float4 b4 = ld4(bias + c);
  ushort4 hv = *(const ushort4*)(h + (size_t)i*CH + c);
  float a0 = b2f(hv.x)*w + b4.x;
  float a1 = b2f(hv.y)*w + b4.y;
  float a2 = b2f(hv.z)*w + b4.z;
  float a3 = b2f(hv.w)*w + b4.w;
  int e0 = offs[i], e1 = offs[i+1];
  int e = e0;
  for (; e + 1 < e1; e += 2){
    int s0 = esrc[e], s1 = esrc[e+1];
    float n0 = enorm[e], n1 = enorm[e+1];
    ushort4 h0 = *(const ushort4*)(h + (size_t)s0*CH + c);
    ushort4 h1 = *(const ushort4*)(h + (size_t)s1*CH + c);
    a0 += b2f(h0.x)*n0; a1 += b2f(h0.y)*n0; a2 += b2f(h0.z)*n0; a3 += b2f(h0.w)*n0;
    a0 += b2f(h1.x)*n1; a1 += b2f(h1.y)*n1; a2 += b2f(h1.z)*n1; a3 += b2f(h1.w)*n1;
  }
  if (e < e1){
    int s0 = esrc[e];
    float n0 = enorm[e];
    ushort4 h0 = *(const ushort4*)(h + (size_t)s0*CH + c);
    a0 += b2f(h0.x)*n0; a1 += b2f(h0.y)*n0; a2 += b2f(h0.z)*n0; a3 += b2f(h0.w)*n0;
  }
  if (RELU){
    a0 = fmaxf(a0,0.f); a1 = fmaxf(a1,0.f); a2 = fmaxf(a2,0.f); a3 = fmaxf(a3,0.f);
  }
  if (OUTBF){
    ushort4 o; o.x=f2b(a0); o.y=f2b(a1); o.z=f2b(a2); o.w=f2b(a3);
    *(ushort4*)((u16*)outv + (size_t)i*CH + c) = o;
  } else {
    *(float4*)((float*)outv + (size_t)i*CH + c) = make_float4(a0,a1,a2,a3);
  }
}

// ---------------- launch ----------------

extern "C" void kernel_launch(void* const* d_in, const int* in_sizes, int n_in,
                              void* d_out, int out_size, void* d_ws, size_t ws_size,
                              hipStream_t stream){
  const float* x  = (const float*)d_in[0];
  const int*   ei = (const int*)d_in[1];
  const float* W1 = (const float*)d_in[2];
  const float* b1 = (const float*)d_in[3];
  const float* W2 = (const float*)d_in[4];
  const float* b2 = (const float*)d_in[5];
  float* out = (float*)d_out;

  const int n = NN;
  const int E = in_sizes[1] / 2;
  const int* src = ei;
  const int* dst = ei + E;
  const int KIN = in_sizes[0] / n;   // 512

  char* ws = (char*)d_ws;
  size_t off = 0;
  auto alloc = [&](size_t bytes)->char* {
    char* p = ws + off;
    off += (bytes + 255) & ~(size_t)255;
    return p;
  };
  u16*   Xbf    = (u16*)  alloc((size_t)n*KIN*sizeof(u16));  // 51.2 MB; later h1bf@0, g2out@n*CH
  u16*   W1bf   = (u16*)  alloc((size_t)CH*KIN*sizeof(u16));
  u16*   W2bf   = (u16*)  alloc((size_t)CH*CH*sizeof(u16));
  float* dinv   = (float*)alloc((size_t)n*sizeof(float));
  int*   cnt    = (int*)  alloc((size_t)n*sizeof(int));
  int*   offs   = (int*)  alloc((size_t)(n+1)*sizeof(int));
  int*   cursor = (int*)  alloc((size_t)n*sizeof(int));
  int*   bsum   = (int*)  alloc(256*sizeof(int));
  int*   esrc   = (int*)  alloc((size_t)E*sizeof(int));
  float* enorm  = (float*)alloc((size_t)E*sizeof(float));
  (void)ws_size;

  u16* g1out = (u16*)d_out;              // GEMM1 bf16 output parks in d_out (25.6 MB of 51.2)
  u16* h1bf  = Xbf;                      // agg1 output (Xbf dead after GEMM1)
  u16* g2out = Xbf + (size_t)n*CH;       // GEMM2 output (disjoint from h1bf)

  // --- CSR + norms ---
  hipMemsetAsync(cnt, 0, (size_t)n*sizeof(int), stream);
  hist_kernel<<<(E+255)/256, 256, 0, stream>>>(dst, cnt, E);
  dinv_kernel<<<(n+255)/256, 256, 0, stream>>>(cnt, dinv, n);
  int nb = (n + 1023) / 1024;            // 49 <= 64
  scan_partial_kernel<<<nb, 256, 0, stream>>>(cnt, bsum, n);
  scan_bsums_kernel<<<1, 64, 0, stream>>>(bsum, nb);
  scan_final_kernel<<<nb, 256, 0, stream>>>(cnt, bsum, offs, cursor, n, E);
  scatter_kernel<<<(E+255)/256, 256, 0, stream>>>(src, dst, dinv, cursor, esrc, enorm, E);

  // --- bf16 conversions ---
  cvt_kernel<<<(n*KIN/4+255)/256, 256, 0, stream>>>(x, Xbf, n*KIN/4);
  cvt_kernel<<<(CH*KIN/4+255)/256, 256, 0, stream>>>(W1, W1bf, CH*KIN/4);
  cvt_kernel<<<(CH*CH/4+255)/256, 256, 0, stream>>>(W2, W2bf, CH*CH/4);

  // --- layer 1: g1out = Xbf @ W1bf^T ; h1bf = relu(agg(g1out) + b1) ---
  dim3 gg((n+127)/128, CH/128);
  gemm_mfma_kernel<<<gg, 256, 0, stream>>>(Xbf, W1bf, g1out, n, KIN);
  aggregate_kernel<true, true><<<(n+3)/4, 256, 0, stream>>>(g1out, b1, dinv, offs, esrc, enorm, h1bf, n);

  // --- layer 2: g2out = h1bf @ W2bf^T ; out = agg(g2out) + b2 ---
  gemm_mfma_kernel<<<gg, 256, 0, stream>>>(h1bf, W2bf, g2out, n, CH);
  aggregate_kernel<false, false><<<(n+3)/4, 256, 0, stream>>>(g2out, b2, dinv, offs, esrc, enorm, out, n);
}